// Round 11
// baseline (76.784 us; speedup 1.0000x reference)
//
#include <hip/hip_runtime.h>
#include <hip/hip_bf16.h>
#include <hip/hip_fp16.h>

// Shapes: n_atoms=50000, hidden=32, num_irreps=16, out_ch=32, n_edges=800000
// 4 plain dispatches, ~48 MB workspace.
// r10 post-mortem: nfT/gcursor fixes ~neutral (-1.3 us) -> acc_gemm gathers
// and coarse-counter contention were NOT the walls. Remaining gap vs the
// ~12 us BW floor is launch-grain parallelism: split had 391 blocks
// (~6 waves/CU), bucket 196 blocks on 256 CUs (60 CUs idle).
// r11: split CHUNK 1024 (782 blocks, 4 edges/thread); bucket group = 128
// atoms (391 blocks x 512 thr); GCAP 4096 (mean 2046, 45-sigma).
//  1) zero_repack : gcursor=0, W -> w2frag bf16, nf -> nfT (paired bf16)
//  2) split       : 1024-edge blocks; inline records; LDS hist(391 bins) ->
//                   one padded global atomicAdd per (block,group) -> 16-B
//                   {src|x, y|z, tgt, 0} run-scatter into gbuf[g*GCAP..].
//  3) bucket      : block g owns atoms [g*128,(g+1)*128): stream gbuf densely,
//                   slot = LDS atomicAdd, 8-B rec -> recs (64 KB L2 slice),
//                   coalesced per-atom counts -> cursor.
//  4) acc_gemm    : 16 waves = 16 atoms; Y->LDS, MFMA aggregation (nfT
//                   gathers), agg->LDS (skewed), final 16x512@512x32 MFMA.

#define HIDDEN 32
#define IRREPS 16
#define OUTCH  32
#define CAP    48     // bucket capacity (16 avg fill; ran clean r0-r10)
#define WPB    16     // waves (=atoms) per acc_gemm block
#define AGP    584    // ldsAgg pitch in shorts (max skewed pos 567)
#define GRP    128    // atoms per radix group
#define GCAP   4096   // gbuf capacity per group (mean 2046)
#define GSTR   16     // gcursor stride in ints (64-B padding)
#define CHUNK  1024   // edges per split block
#define NGMAX  512    // LDS hist array size (>= ngroups = 391)
#define C0SH   0.28209479177387814f

typedef __attribute__((ext_vector_type(8))) short frag8;
typedef __attribute__((ext_vector_type(4))) float f32x4;
typedef __attribute__((ext_vector_type(4))) unsigned int u32x4v;

__device__ __forceinline__ unsigned short bf16bits(float f) {
    __hip_bfloat16 t = __float2bfloat16(f);
    return *(unsigned short*)&t;
}
__device__ __forceinline__ unsigned short f16bits(float f) {
    __half h = __float2half(f);
    return *(unsigned short*)&h;
}
__device__ __forceinline__ float f16tof(unsigned short u) {
    __half h = *(__half*)&u;
    return __half2float(h);
}
__device__ __forceinline__ frag8 mkfrag(unsigned a, unsigned b, unsigned c, unsigned d) {
    u32x4v v = {a, b, c, d};
    return __builtin_bit_cast(frag8, v);
}

// ---------------- 1: zero gcursor + repack W + nf->nfT ----------------------
__global__ __launch_bounds__(256)
void zero_repack_kernel(const float* __restrict__ W,
                        const float* __restrict__ nf,
                        int* __restrict__ gcursor,
                        unsigned* __restrict__ nfT,
                        __hip_bfloat16* __restrict__ w2frag,
                        int n_atoms, int ngroups) {
    const int tid = blockIdx.x * blockDim.x + threadIdx.x;
    const int gsz = gridDim.x * blockDim.x;
    if (tid < ngroups * GSTR) gcursor[tid] = 0;
    // nfT[s][m] = {bf16 nf[s][m] | bf16 nf[s][m+16]}; one uint4 per (s, m-quad)
    const int tq = n_atoms * 4;
    for (int i = tid; i < tq; i += gsz) {
        const int s = i >> 2, q = (i & 3) * 4;
        const float4 lo = *(const float4*)(nf + s * HIDDEN + q);
        const float4 hi = *(const float4*)(nf + s * HIDDEN + 16 + q);
        uint4 o;
        o.x = (unsigned)bf16bits(lo.x) | ((unsigned)bf16bits(hi.x) << 16);
        o.y = (unsigned)bf16bits(lo.y) | ((unsigned)bf16bits(hi.y) << 16);
        o.z = (unsigned)bf16bits(lo.z) | ((unsigned)bf16bits(hi.z) << 16);
        o.w = (unsigned)bf16bits(lo.w) | ((unsigned)bf16bits(hi.w) << 16);
        *(uint4*)(nfT + s * 16 + q) = o;
    }
    if (tid < 2048) {
        const int lane = tid & 63;
        const int kk   = tid >> 7;
        const int n    = (((tid >> 6) & 1) << 4) + (lane & 15);
        const int kb   = kk * 32 + (lane >> 4) * 8;
#pragma unroll
        for (int j = 0; j < 8; ++j)
            w2frag[tid * 8 + j] = __float2bfloat16(W[(kb + j) * OUTCH + n]);
    }
}

// ---------------- 2: split — coarse radix pass, LDS hist + run reserve ------
__global__ __launch_bounds__(256)
void split_kernel(const float* __restrict__ ev,
                  const int* __restrict__ ei,
                  int* __restrict__ gcursor,
                  uint4* __restrict__ gbuf,
                  int n_edges, int ngroups) {
    __shared__ int hist[NGMAX];
    __shared__ int cur[NGMAX];
    for (int b = threadIdx.x; b < NGMAX; b += 256) hist[b] = 0;
    __syncthreads();

    const int e0 = blockIdx.x * CHUNK + threadIdx.x * 4;
    int   sr[4], tg[4];
    float vx[4], vy[4], vz[4];
    const int cnt = min(max(n_edges - e0, 0), 4);
    if (cnt == 4) {
        // e0 % 4 == 0 -> int4 loads and the 3 float4 loads are 16-B aligned
        const int4 s4 = *(const int4*)(ei + e0);
        const int4 t4 = *(const int4*)(ei + n_edges + e0);
        sr[0]=s4.x; sr[1]=s4.y; sr[2]=s4.z; sr[3]=s4.w;
        tg[0]=t4.x; tg[1]=t4.y; tg[2]=t4.z; tg[3]=t4.w;
        const float4 a  = *(const float4*)(ev + 3 * e0 + 0);
        const float4 bq = *(const float4*)(ev + 3 * e0 + 4);
        const float4 cq = *(const float4*)(ev + 3 * e0 + 8);
        vx[0]=a.x;  vy[0]=a.y;  vz[0]=a.z;
        vx[1]=a.w;  vy[1]=bq.x; vz[1]=bq.y;
        vx[2]=bq.z; vy[2]=bq.w; vz[2]=cq.x;
        vx[3]=cq.y; vy[3]=cq.z; vz[3]=cq.w;
    } else {
        for (int j = 0; j < cnt; ++j) {
            const int e = e0 + j;
            sr[j] = ei[e];
            tg[j] = ei[n_edges + e];
            vx[j] = ev[3*e]; vy[j] = ev[3*e+1]; vz[j] = ev[3*e+2];
        }
    }

    for (int j = 0; j < cnt; ++j) atomicAdd(&hist[tg[j] >> 7], 1);
    __syncthreads();
    for (int b = threadIdx.x; b < ngroups; b += 256) {
        const int h = hist[b];
        cur[b] = h ? atomicAdd(&gcursor[b * GSTR], h) : 0;
    }
    __syncthreads();

    for (int j = 0; j < cnt; ++j) {
        const int g = tg[j] >> 7;
        const int pos = atomicAdd(&cur[g], 1);            // LDS; base+i
        if (pos >= GCAP) continue;
        const float rinv = 1.0f /
            fmaxf(sqrtf(vx[j]*vx[j] + vy[j]*vy[j] + vz[j]*vz[j]), 1e-12f);
        uint4 r;
        r.x = (unsigned)(sr[j] & 0xffff) | ((unsigned)f16bits(vx[j]*rinv) << 16);
        r.y = (unsigned)f16bits(vy[j]*rinv) | ((unsigned)f16bits(vz[j]*rinv) << 16);
        r.z = (unsigned)tg[j];
        r.w = 0u;
        gbuf[(size_t)g * GCAP + pos] = r;
    }
}

// ---------------- 3: bucket — fine pass, exclusive range, LDS cursors -------
__global__ __launch_bounds__(512)
void bucket_kernel(const uint4* __restrict__ gbuf,
                   const int* __restrict__ gcursor,
                   uint2* __restrict__ recs,
                   int* __restrict__ cursor,
                   int n_atoms) {
    __shared__ int lcur[GRP];
    const int g = blockIdx.x;
    if (threadIdx.x < GRP) lcur[threadIdx.x] = 0;
    __syncthreads();
    const int n = min(gcursor[g * GSTR], GCAP);
    const uint4* gb = gbuf + (size_t)g * GCAP;
    for (int i = threadIdx.x; i < n; i += 512) {
        const uint4 r = gb[i];                            // dense 16-B stream
        const int tgt = (int)r.z;
        const int slot = atomicAdd(&lcur[tgt & (GRP - 1)], 1);  // LDS, ~30 cy
        if (slot < CAP) {
            uint2 d; d.x = r.x; d.y = r.y;
            recs[(size_t)tgt * CAP + slot] = d;           // 64 KB L2-local slice
        }
    }
    __syncthreads();
    const int a = g * GRP + threadIdx.x;
    if (threadIdx.x < GRP && a < n_atoms)
        cursor[a] = lcur[threadIdx.x];                    // coalesced counts
}

// ---------------- 4: fused MFMA-aggregate + GEMM (unchanged from r10) -------
__global__ __launch_bounds__(1024, 8)
void acc_gemm_kernel(const uint2* __restrict__ recs,
                     const int* __restrict__ cursor,
                     const unsigned* __restrict__ nfT,
                     const __hip_bfloat16* __restrict__ w2frag,
                     const float* __restrict__ bias,
                     float* __restrict__ out,
                     int n_atoms) {
    __shared__ short ldsY[WPB][64 * 18];   // 36864 B: Y rows, 18-short pitch
    __shared__ short ldsAgg[WPB][AGP];     // 18688 B: agg rows, global skew
    __shared__ int   ldsS[WPB][64];        //  4096 B: src*16 (0-padded)
    const int wv   = threadIdx.x >> 6;     // wave id = local atom id
    const int lane = threadIdx.x & 63;
    const int w    = min(blockIdx.x * WPB + wv, n_atoms - 1);

    const int k = min(max(__builtin_amdgcn_readfirstlane(cursor[w]), 0), CAP);

    // ---- phase A: Y rows (one edge per lane; zero rows pad K to 64) --------
    {
        float Yv[16];
#pragma unroll
        for (int q = 0; q < 16; ++q) Yv[q] = 0.f;
        int s = 0;
        if (lane < k) {
            const uint2 rec = recs[(size_t)w * CAP + lane];   // coalesced 8 B
            s = (int)(rec.x & 0xffffu);
            const float x = f16tof((unsigned short)(rec.x >> 16));
            const float y = f16tof((unsigned short)(rec.y & 0xffffu));
            const float z = f16tof((unsigned short)(rec.y >> 16));
            const float x2 = x * x, y2 = y * y, z2 = z * z;
            const float xy = x * y, yz = y * z, xz = x * z;
            const float xmy = x2 - y2;
            const float fz2 = fmaf(5.0f, z2, -1.0f);
            Yv[0]  = C0SH;
            Yv[1]  = 0.4886025119029199f * y;
            Yv[2]  = 0.4886025119029199f * z;
            Yv[3]  = 0.4886025119029199f * x;
            Yv[4]  = 1.0925484305920792f * xy;
            Yv[5]  = 1.0925484305920792f * yz;
            Yv[6]  = 0.31539156525252005f * fmaf(3.0f, z2, -1.0f);
            Yv[7]  = 1.0925484305920792f * xz;
            Yv[8]  = 0.5462742152960396f * xmy;
            Yv[9]  = 0.5900435899266435f * y * fmaf(2.0f, x2, xmy);
            Yv[10] = 2.890611442640554f * xy * z;
            Yv[11] = 0.4570457994644658f * y * fz2;
            Yv[12] = 0.3731763325901154f * z * fmaf(5.0f, z2, -3.0f);
            Yv[13] = 0.4570457994644658f * x * fz2;
            Yv[14] = 1.445305721320277f * z * xmy;
            Yv[15] = 0.5900435899266435f * x * fmaf(-3.0f, y2, x2);
        }
        ldsS[wv][lane] = s << 4;           // premultiplied nfT row offset
        short* yr = &ldsY[wv][lane * 18];
#pragma unroll
        for (int d = 0; d < 8; ++d)
            *(unsigned*)&yr[d * 2] =
                (unsigned)bf16bits(Yv[2 * d]) | ((unsigned)bf16bits(Yv[2 * d + 1]) << 16);
    }
    // order phase-A ds_writes before phase-B ds_reads (same-wave cross-lane)
    asm volatile("s_waitcnt lgkmcnt(0)" ::: "memory");
    __builtin_amdgcn_sched_barrier(0);

    // ---- phase B: MFMA aggregation (nfT paired-h gathers) ------------------
    const int kq = lane >> 4;
    const int m  = lane & 15;     // A: h within tile; B: irrep i; C: col i
    f32x4 acc0 = {0.f, 0.f, 0.f, 0.f};
    f32x4 acc1 = {0.f, 0.f, 0.f, 0.f};
    {
        const short* yrow = &ldsY[wv][0];
        const int* sv = &ldsS[wv][0];
        const int nks = (k > 32) ? 2 : 1;
        for (int ks = 0; ks < nks; ++ks) {
            const int e0 = ks * 32 + kq * 8;
            unsigned g[8];
#pragma unroll
            for (int j = 0; j < 8; ++j)
                g[j] = nfT[sv[e0 + j] + m];   // {nf[s][m] | nf[s][m+16]}
            unsigned bu[4], au0[4], au1[4];
#pragma unroll
            for (int p = 0; p < 4; ++p) {
                const unsigned ylo = *(const unsigned short*)&yrow[(e0 + 2 * p) * 18 + m];
                const unsigned yhi = *(const unsigned short*)&yrow[(e0 + 2 * p + 1) * 18 + m];
                bu[p] = ylo | (yhi << 16);
                const unsigned g0 = g[2 * p], g1 = g[2 * p + 1];
                au0[p] = (g0 & 0xffffu) | (g1 << 16);
                au1[p] = (g0 >> 16) | (g1 & 0xffff0000u);
            }
            const frag8 bf = mkfrag(bu[0], bu[1], bu[2], bu[3]);
            acc0 = __builtin_amdgcn_mfma_f32_16x16x32_bf16(
                mkfrag(au0[0], au0[1], au0[2], au0[3]), bf, acc0, 0, 0, 0);
            acc1 = __builtin_amdgcn_mfma_f32_16x16x32_bf16(
                mkfrag(au1[0], au1[1], au1[2], au1[3]), bf, acc1, 0, 0, 0);
        }
    }

    // ---- phase C: C-frags -> bf16 agg row at pos(k) = k + (k>>6)*8 ---------
    {
        short* arow = &ldsAgg[wv][0];
#pragma unroll
        for (int r = 0; r < 4; ++r) {
            arow[kq * 72 + r * 16 + m]       = (short)bf16bits(acc0[r]);
            arow[kq * 72 + r * 16 + m + 288] = (short)bf16bits(acc1[r]);
        }
    }

    __syncthreads();

    // ---- final GEMM: out[16 atoms][32] = agg @ W + b, waves 0,1 = N-halves -
    if (wv < 2) {
        const int m2   = lane & 15;       // atom within tile
        const int quad = lane >> 4;
        const int nh   = wv;
        const short* wf = (const short*)w2frag;
        f32x4 acc = {0.f, 0.f, 0.f, 0.f};
#pragma unroll
        for (int kk = 0; kk < 16; ++kk) {
            const int sidx = kk * 32 + quad * 8 + (kk >> 1) * 8;
            frag8 a  = *(const frag8*)&ldsAgg[m2][sidx];
            frag8 bb = *(const frag8*)(wf + ((kk * 2 + nh) * 64 + lane) * 8);
            acc = __builtin_amdgcn_mfma_f32_16x16x32_bf16(a, bb, acc, 0, 0, 0);
        }
        const float bi = bias[nh * 16 + m2];
        const int tile0 = blockIdx.x * WPB;
#pragma unroll
        for (int r = 0; r < 4; ++r) {
            const int row = tile0 + quad * 4 + r;   // D: row=quad*4+r, col=m2
            if (row < n_atoms)
                out[(size_t)row * OUTCH + nh * 16 + m2] = acc[r] + bi;
        }
    }
}

// ---------------- launch ---------------------------------------------------
extern "C" void kernel_launch(void* const* d_in, const int* in_sizes, int n_in,
                              void* d_out, int out_size, void* d_ws, size_t ws_size,
                              hipStream_t stream) {
    const float* nf = (const float*)d_in[0];
    const float* ev = (const float*)d_in[1];
    const int*   ei = (const int*)d_in[2];
    const float* W  = (const float*)d_in[3];
    const float* b  = (const float*)d_in[4];
    float* out = (float*)d_out;

    const int n_atoms = in_sizes[0] / HIDDEN;
    const int n_edges = in_sizes[1] / 3;
    const int ngroups = (n_atoms + GRP - 1) / GRP;   // 391

    char* ws = (char*)d_ws;
    size_t off = 0;
    auto carve = [&](size_t bytes) { void* p = ws + off; off = (off + bytes + 255) & ~(size_t)255; return p; };
    uint2*          recs    = (uint2*)carve((size_t)n_atoms * CAP * 8);    // 19.2 MB
    uint4*          gbuf    = (uint4*)carve((size_t)ngroups * GCAP * 16);  // 25.6 MB
    unsigned*       nfT     = (unsigned*)carve((size_t)n_atoms * 16 * 4);  //  3.2 MB
    __hip_bfloat16* w2frag  = (__hip_bfloat16*)carve(2048 * 8 * 2);        //  32 KB
    int*            cursor  = (int*)carve((size_t)n_atoms * 4);            //  0.2 MB
    int*            gcursor = (int*)carve((size_t)ngroups * GSTR * 4);     //  25 KB

    zero_repack_kernel<<<512, 256, 0, stream>>>(W, nf, gcursor, nfT, w2frag,
                                                n_atoms, ngroups);

    const int sblocks = (n_edges + CHUNK - 1) / CHUNK;
    split_kernel<<<sblocks, 256, 0, stream>>>(ev, ei, gcursor, gbuf, n_edges, ngroups);

    bucket_kernel<<<ngroups, 512, 0, stream>>>(gbuf, gcursor, recs, cursor, n_atoms);

    const int blocks3 = (n_atoms + WPB - 1) / WPB;
    acc_gemm_kernel<<<blocks3, WPB * 64, 0, stream>>>(
        recs, cursor, nfT, w2frag, b, out, n_atoms);
}

// Round 12
// 58.711 us; speedup vs baseline: 1.3078x; 1.3078x over previous
//
#include <hip/hip_runtime.h>
#include <hip/hip_bf16.h>
#include <hip/hip_fp16.h>

// Shapes: n_atoms=50000, hidden=32, num_irreps=16, out_ch=32, n_edges=800000
// 4 plain dispatches, ~48 MB workspace.
// r11 post-mortem: finer grain (CHUNK 1024 / GRP 128) REGRESSED 58.9->76.8:
// run length = CHUNK/ngroups fell 10.4->2.6, reverting the run-scatter to
// isolated 16-B sector writes + 3x reserve atomics. Rule: never shrink the
// run-length ratio. r12 = r10 config restored (CHUNK 2048, GRP 256) with
// split at 512 thr x 4 edges (same 391 blocks, same hist/run structure, but
// 2x waves and half the per-thread serial scatter chain).
//  1) zero_repack : gcursor=0, W -> w2frag bf16, nf -> nfT (paired bf16)
//  2) split       : 2048-edge blocks, 512 thr; LDS hist(196 bins) -> one
//                   padded global atomicAdd per (block,group) -> 16-B
//                   {src|x, y|z, tgt, 0} run-scatter into gbuf[g*GCAP..].
//  3) bucket      : block g owns atoms [g*256,(g+1)*256): stream gbuf densely,
//                   slot = LDS atomicAdd, 8-B rec -> recs (L2-local slice),
//                   coalesced per-atom counts -> cursor.
//  4) acc_gemm    : 16 waves = 16 atoms; Y->LDS, MFMA aggregation (nfT
//                   paired-h gathers), agg->LDS (skewed), final MFMA GEMM.

#define HIDDEN 32
#define IRREPS 16
#define OUTCH  32
#define CAP    48     // bucket capacity (16 avg fill; ran clean r0-r10)
#define WPB    16     // waves (=atoms) per acc_gemm block
#define AGP    584    // ldsAgg pitch in shorts (max skewed pos 567)
#define GRP    256    // atoms per radix group
#define GCAP   8192   // gbuf capacity per group (mean 4096)
#define GSTR   16     // gcursor stride in ints (64-B padding)
#define CHUNK  2048   // edges per split block
#define C0SH   0.28209479177387814f

typedef __attribute__((ext_vector_type(8))) short frag8;
typedef __attribute__((ext_vector_type(4))) float f32x4;
typedef __attribute__((ext_vector_type(4))) unsigned int u32x4v;

__device__ __forceinline__ unsigned short bf16bits(float f) {
    __hip_bfloat16 t = __float2bfloat16(f);
    return *(unsigned short*)&t;
}
__device__ __forceinline__ unsigned short f16bits(float f) {
    __half h = __float2half(f);
    return *(unsigned short*)&h;
}
__device__ __forceinline__ float f16tof(unsigned short u) {
    __half h = *(__half*)&u;
    return __half2float(h);
}
__device__ __forceinline__ frag8 mkfrag(unsigned a, unsigned b, unsigned c, unsigned d) {
    u32x4v v = {a, b, c, d};
    return __builtin_bit_cast(frag8, v);
}

// ---------------- 1: zero gcursor + repack W + nf->nfT ----------------------
__global__ __launch_bounds__(256)
void zero_repack_kernel(const float* __restrict__ W,
                        const float* __restrict__ nf,
                        int* __restrict__ gcursor,
                        unsigned* __restrict__ nfT,
                        __hip_bfloat16* __restrict__ w2frag,
                        int n_atoms, int ngroups) {
    const int tid = blockIdx.x * blockDim.x + threadIdx.x;
    const int gsz = gridDim.x * blockDim.x;
    if (tid < ngroups * GSTR) gcursor[tid] = 0;
    // nfT[s][m] = {bf16 nf[s][m] | bf16 nf[s][m+16]}; one uint4 per (s, m-quad)
    const int tq = n_atoms * 4;
    for (int i = tid; i < tq; i += gsz) {
        const int s = i >> 2, q = (i & 3) * 4;
        const float4 lo = *(const float4*)(nf + s * HIDDEN + q);
        const float4 hi = *(const float4*)(nf + s * HIDDEN + 16 + q);
        uint4 o;
        o.x = (unsigned)bf16bits(lo.x) | ((unsigned)bf16bits(hi.x) << 16);
        o.y = (unsigned)bf16bits(lo.y) | ((unsigned)bf16bits(hi.y) << 16);
        o.z = (unsigned)bf16bits(lo.z) | ((unsigned)bf16bits(hi.z) << 16);
        o.w = (unsigned)bf16bits(lo.w) | ((unsigned)bf16bits(hi.w) << 16);
        *(uint4*)(nfT + s * 16 + q) = o;
    }
    if (tid < 2048) {
        const int lane = tid & 63;
        const int kk   = tid >> 7;
        const int n    = (((tid >> 6) & 1) << 4) + (lane & 15);
        const int kb   = kk * 32 + (lane >> 4) * 8;
#pragma unroll
        for (int j = 0; j < 8; ++j)
            w2frag[tid * 8 + j] = __float2bfloat16(W[(kb + j) * OUTCH + n]);
    }
}

// ---------------- 2: split — coarse radix pass, LDS hist + run reserve ------
__global__ __launch_bounds__(512)
void split_kernel(const float* __restrict__ ev,
                  const int* __restrict__ ei,
                  int* __restrict__ gcursor,
                  uint4* __restrict__ gbuf,
                  int n_edges) {
    __shared__ int hist[256];
    __shared__ int cur[256];
    if (threadIdx.x < 256) hist[threadIdx.x] = 0;
    __syncthreads();

    const int e0 = blockIdx.x * CHUNK + threadIdx.x * 4;
    int   sr[4], tg[4];
    float vx[4], vy[4], vz[4];
    const int cnt = min(max(n_edges - e0, 0), 4);
    if (cnt == 4) {
        // e0 % 4 == 0 -> int4 loads and the 3 float4 loads are 16-B aligned
        const int4 s4 = *(const int4*)(ei + e0);
        const int4 t4 = *(const int4*)(ei + n_edges + e0);
        sr[0]=s4.x; sr[1]=s4.y; sr[2]=s4.z; sr[3]=s4.w;
        tg[0]=t4.x; tg[1]=t4.y; tg[2]=t4.z; tg[3]=t4.w;
        const float4 a  = *(const float4*)(ev + 3 * e0 + 0);
        const float4 bq = *(const float4*)(ev + 3 * e0 + 4);
        const float4 cq = *(const float4*)(ev + 3 * e0 + 8);
        vx[0]=a.x;  vy[0]=a.y;  vz[0]=a.z;
        vx[1]=a.w;  vy[1]=bq.x; vz[1]=bq.y;
        vx[2]=bq.z; vy[2]=bq.w; vz[2]=cq.x;
        vx[3]=cq.y; vy[3]=cq.z; vz[3]=cq.w;
    } else {
        for (int j = 0; j < cnt; ++j) {
            const int e = e0 + j;
            sr[j] = ei[e];
            tg[j] = ei[n_edges + e];
            vx[j] = ev[3*e]; vy[j] = ev[3*e+1]; vz[j] = ev[3*e+2];
        }
    }

    for (int j = 0; j < cnt; ++j) atomicAdd(&hist[tg[j] >> 8], 1);
    __syncthreads();
    if (threadIdx.x < 256) {
        const int h = hist[threadIdx.x];
        cur[threadIdx.x] = h ? atomicAdd(&gcursor[threadIdx.x * GSTR], h) : 0;
    }
    __syncthreads();

    for (int j = 0; j < cnt; ++j) {
        const int g = tg[j] >> 8;
        const int pos = atomicAdd(&cur[g], 1);            // LDS; base+i
        if (pos >= GCAP) continue;
        const float rinv = 1.0f /
            fmaxf(sqrtf(vx[j]*vx[j] + vy[j]*vy[j] + vz[j]*vz[j]), 1e-12f);
        uint4 r;
        r.x = (unsigned)(sr[j] & 0xffff) | ((unsigned)f16bits(vx[j]*rinv) << 16);
        r.y = (unsigned)f16bits(vy[j]*rinv) | ((unsigned)f16bits(vz[j]*rinv) << 16);
        r.z = (unsigned)tg[j];
        r.w = 0u;
        gbuf[(size_t)g * GCAP + pos] = r;
    }
}

// ---------------- 3: bucket — fine pass, exclusive range, LDS cursors -------
__global__ __launch_bounds__(1024)
void bucket_kernel(const uint4* __restrict__ gbuf,
                   const int* __restrict__ gcursor,
                   uint2* __restrict__ recs,
                   int* __restrict__ cursor,
                   int n_atoms) {
    __shared__ int lcur[GRP];
    const int g = blockIdx.x;
    if (threadIdx.x < GRP) lcur[threadIdx.x] = 0;
    __syncthreads();
    const int n = min(gcursor[g * GSTR], GCAP);
    const uint4* gb = gbuf + (size_t)g * GCAP;
    for (int i = threadIdx.x; i < n; i += 1024) {
        const uint4 r = gb[i];                            // dense 16-B stream
        const int tgt = (int)r.z;
        const int slot = atomicAdd(&lcur[tgt & (GRP - 1)], 1);  // LDS, ~30 cy
        if (slot < CAP) {
            uint2 d; d.x = r.x; d.y = r.y;
            recs[(size_t)tgt * CAP + slot] = d;           // L2-local slice
        }
    }
    __syncthreads();
    const int a = g * GRP + threadIdx.x;
    if (threadIdx.x < GRP && a < n_atoms)
        cursor[a] = lcur[threadIdx.x];                    // coalesced counts
}

// ---------------- 4: fused MFMA-aggregate + GEMM (unchanged from r10) -------
__global__ __launch_bounds__(1024, 8)
void acc_gemm_kernel(const uint2* __restrict__ recs,
                     const int* __restrict__ cursor,
                     const unsigned* __restrict__ nfT,
                     const __hip_bfloat16* __restrict__ w2frag,
                     const float* __restrict__ bias,
                     float* __restrict__ out,
                     int n_atoms) {
    __shared__ short ldsY[WPB][64 * 18];   // 36864 B: Y rows, 18-short pitch
    __shared__ short ldsAgg[WPB][AGP];     // 18688 B: agg rows, global skew
    __shared__ int   ldsS[WPB][64];        //  4096 B: src*16 (0-padded)
    const int wv   = threadIdx.x >> 6;     // wave id = local atom id
    const int lane = threadIdx.x & 63;
    const int w    = min(blockIdx.x * WPB + wv, n_atoms - 1);

    const int k = min(max(__builtin_amdgcn_readfirstlane(cursor[w]), 0), CAP);

    // ---- phase A: Y rows (one edge per lane; zero rows pad K to 64) --------
    {
        float Yv[16];
#pragma unroll
        for (int q = 0; q < 16; ++q) Yv[q] = 0.f;
        int s = 0;
        if (lane < k) {
            const uint2 rec = recs[(size_t)w * CAP + lane];   // coalesced 8 B
            s = (int)(rec.x & 0xffffu);
            const float x = f16tof((unsigned short)(rec.x >> 16));
            const float y = f16tof((unsigned short)(rec.y & 0xffffu));
            const float z = f16tof((unsigned short)(rec.y >> 16));
            const float x2 = x * x, y2 = y * y, z2 = z * z;
            const float xy = x * y, yz = y * z, xz = x * z;
            const float xmy = x2 - y2;
            const float fz2 = fmaf(5.0f, z2, -1.0f);
            Yv[0]  = C0SH;
            Yv[1]  = 0.4886025119029199f * y;
            Yv[2]  = 0.4886025119029199f * z;
            Yv[3]  = 0.4886025119029199f * x;
            Yv[4]  = 1.0925484305920792f * xy;
            Yv[5]  = 1.0925484305920792f * yz;
            Yv[6]  = 0.31539156525252005f * fmaf(3.0f, z2, -1.0f);
            Yv[7]  = 1.0925484305920792f * xz;
            Yv[8]  = 0.5462742152960396f * xmy;
            Yv[9]  = 0.5900435899266435f * y * fmaf(2.0f, x2, xmy);
            Yv[10] = 2.890611442640554f * xy * z;
            Yv[11] = 0.4570457994644658f * y * fz2;
            Yv[12] = 0.3731763325901154f * z * fmaf(5.0f, z2, -3.0f);
            Yv[13] = 0.4570457994644658f * x * fz2;
            Yv[14] = 1.445305721320277f * z * xmy;
            Yv[15] = 0.5900435899266435f * x * fmaf(-3.0f, y2, x2);
        }
        ldsS[wv][lane] = s << 4;           // premultiplied nfT row offset
        short* yr = &ldsY[wv][lane * 18];
#pragma unroll
        for (int d = 0; d < 8; ++d)
            *(unsigned*)&yr[d * 2] =
                (unsigned)bf16bits(Yv[2 * d]) | ((unsigned)bf16bits(Yv[2 * d + 1]) << 16);
    }
    // order phase-A ds_writes before phase-B ds_reads (same-wave cross-lane)
    asm volatile("s_waitcnt lgkmcnt(0)" ::: "memory");
    __builtin_amdgcn_sched_barrier(0);

    // ---- phase B: MFMA aggregation (nfT paired-h gathers) ------------------
    const int kq = lane >> 4;
    const int m  = lane & 15;     // A: h within tile; B: irrep i; C: col i
    f32x4 acc0 = {0.f, 0.f, 0.f, 0.f};
    f32x4 acc1 = {0.f, 0.f, 0.f, 0.f};
    {
        const short* yrow = &ldsY[wv][0];
        const int* sv = &ldsS[wv][0];
        const int nks = (k > 32) ? 2 : 1;
        for (int ks = 0; ks < nks; ++ks) {
            const int e0 = ks * 32 + kq * 8;
            unsigned g[8];
#pragma unroll
            for (int j = 0; j < 8; ++j)
                g[j] = nfT[sv[e0 + j] + m];   // {nf[s][m] | nf[s][m+16]}
            unsigned bu[4], au0[4], au1[4];
#pragma unroll
            for (int p = 0; p < 4; ++p) {
                const unsigned ylo = *(const unsigned short*)&yrow[(e0 + 2 * p) * 18 + m];
                const unsigned yhi = *(const unsigned short*)&yrow[(e0 + 2 * p + 1) * 18 + m];
                bu[p] = ylo | (yhi << 16);
                const unsigned g0 = g[2 * p], g1 = g[2 * p + 1];
                au0[p] = (g0 & 0xffffu) | (g1 << 16);
                au1[p] = (g0 >> 16) | (g1 & 0xffff0000u);
            }
            const frag8 bf = mkfrag(bu[0], bu[1], bu[2], bu[3]);
            acc0 = __builtin_amdgcn_mfma_f32_16x16x32_bf16(
                mkfrag(au0[0], au0[1], au0[2], au0[3]), bf, acc0, 0, 0, 0);
            acc1 = __builtin_amdgcn_mfma_f32_16x16x32_bf16(
                mkfrag(au1[0], au1[1], au1[2], au1[3]), bf, acc1, 0, 0, 0);
        }
    }

    // ---- phase C: C-frags -> bf16 agg row at pos(k) = k + (k>>6)*8 ---------
    {
        short* arow = &ldsAgg[wv][0];
#pragma unroll
        for (int r = 0; r < 4; ++r) {
            arow[kq * 72 + r * 16 + m]       = (short)bf16bits(acc0[r]);
            arow[kq * 72 + r * 16 + m + 288] = (short)bf16bits(acc1[r]);
        }
    }

    __syncthreads();

    // ---- final GEMM: out[16 atoms][32] = agg @ W + b, waves 0,1 = N-halves -
    if (wv < 2) {
        const int m2   = lane & 15;       // atom within tile
        const int quad = lane >> 4;
        const int nh   = wv;
        const short* wf = (const short*)w2frag;
        f32x4 acc = {0.f, 0.f, 0.f, 0.f};
#pragma unroll
        for (int kk = 0; kk < 16; ++kk) {
            const int sidx = kk * 32 + quad * 8 + (kk >> 1) * 8;
            frag8 a  = *(const frag8*)&ldsAgg[m2][sidx];
            frag8 bb = *(const frag8*)(wf + ((kk * 2 + nh) * 64 + lane) * 8);
            acc = __builtin_amdgcn_mfma_f32_16x16x32_bf16(a, bb, acc, 0, 0, 0);
        }
        const float bi = bias[nh * 16 + m2];
        const int tile0 = blockIdx.x * WPB;
#pragma unroll
        for (int r = 0; r < 4; ++r) {
            const int row = tile0 + quad * 4 + r;   // D: row=quad*4+r, col=m2
            if (row < n_atoms)
                out[(size_t)row * OUTCH + nh * 16 + m2] = acc[r] + bi;
        }
    }
}

// ---------------- launch ---------------------------------------------------
extern "C" void kernel_launch(void* const* d_in, const int* in_sizes, int n_in,
                              void* d_out, int out_size, void* d_ws, size_t ws_size,
                              hipStream_t stream) {
    const float* nf = (const float*)d_in[0];
    const float* ev = (const float*)d_in[1];
    const int*   ei = (const int*)d_in[2];
    const float* W  = (const float*)d_in[3];
    const float* b  = (const float*)d_in[4];
    float* out = (float*)d_out;

    const int n_atoms = in_sizes[0] / HIDDEN;
    const int n_edges = in_sizes[1] / 3;
    const int ngroups = (n_atoms + GRP - 1) / GRP;   // 196

    char* ws = (char*)d_ws;
    size_t off = 0;
    auto carve = [&](size_t bytes) { void* p = ws + off; off = (off + bytes + 255) & ~(size_t)255; return p; };
    uint2*          recs    = (uint2*)carve((size_t)n_atoms * CAP * 8);    // 19.2 MB
    uint4*          gbuf    = (uint4*)carve((size_t)ngroups * GCAP * 16);  // 25.7 MB
    unsigned*       nfT     = (unsigned*)carve((size_t)n_atoms * 16 * 4);  //  3.2 MB
    __hip_bfloat16* w2frag  = (__hip_bfloat16*)carve(2048 * 8 * 2);        //  32 KB
    int*            cursor  = (int*)carve((size_t)n_atoms * 4);            //  0.2 MB
    int*            gcursor = (int*)carve((size_t)ngroups * GSTR * 4);     //  13 KB

    zero_repack_kernel<<<512, 256, 0, stream>>>(W, nf, gcursor, nfT, w2frag,
                                                n_atoms, ngroups);

    const int sblocks = (n_edges + CHUNK - 1) / CHUNK;
    split_kernel<<<sblocks, 512, 0, stream>>>(ev, ei, gcursor, gbuf, n_edges);

    bucket_kernel<<<ngroups, 1024, 0, stream>>>(gbuf, gcursor, recs, cursor, n_atoms);

    const int blocks3 = (n_atoms + WPB - 1) / WPB;
    acc_gemm_kernel<<<blocks3, WPB * 64, 0, stream>>>(
        recs, cursor, nfT, w2frag, b, out, n_atoms);
}

// Round 14
// 58.533 us; speedup vs baseline: 1.3118x; 1.0030x over previous
//
#include <hip/hip_runtime.h>
#include <hip/hip_bf16.h>
#include <hip/hip_fp16.h>

// Shapes: n_atoms=50000, hidden=32, num_irreps=16, out_ch=32, n_edges=800000
// 4 plain dispatches (one is a 1-block zero), ~48 MB workspace.
// r13 was an infra failure (container died; kernel never measured). r14 =
// same kernel, with the hipMemsetAsync replaced by a 1-block zero kernel to
// remove the only untested-API variable from the launch path.
//  1) zero_g      : gcursor = 0 (12.5 KB, 1 block).
//  2) split       : repack (nf->nfT paired bf16, W->w2frag) folded in +
//                   2048-edge blocks, 512 thr; LDS hist(196 bins) -> one
//                   padded global atomicAdd per (block,group) -> 16-B
//                   {src|x, y|z, tgt, 0} run-scatter into gbuf[g*GCAP..].
//  3) bucket      : block g owns atoms [g*256,(g+1)*256): stream gbuf densely,
//                   slot = LDS atomicAdd, 8-B rec -> recs (L2-local slice),
//                   coalesced per-atom counts -> cursor.
//  4) acc_gemm    : 16 waves = 16 atoms; Y->LDS, MFMA aggregation (nfT
//                   paired-h gathers), agg->LDS (skewed), final MFMA GEMM.

#define HIDDEN 32
#define IRREPS 16
#define OUTCH  32
#define CAP    48     // bucket capacity (16 avg fill; ran clean r0-r12)
#define WPB    16     // waves (=atoms) per acc_gemm block
#define AGP    584    // ldsAgg pitch in shorts (max skewed pos 567)
#define GRP    256    // atoms per radix group
#define GCAP   8192   // gbuf capacity per group (mean 4096)
#define GSTR   16     // gcursor stride in ints (64-B padding)
#define CHUNK  2048   // edges per split block
#define C0SH   0.28209479177387814f

typedef __attribute__((ext_vector_type(8))) short frag8;
typedef __attribute__((ext_vector_type(4))) float f32x4;
typedef __attribute__((ext_vector_type(4))) unsigned int u32x4v;

__device__ __forceinline__ unsigned short bf16bits(float f) {
    __hip_bfloat16 t = __float2bfloat16(f);
    return *(unsigned short*)&t;
}
__device__ __forceinline__ unsigned short f16bits(float f) {
    __half h = __float2half(f);
    return *(unsigned short*)&h;
}
__device__ __forceinline__ float f16tof(unsigned short u) {
    __half h = *(__half*)&u;
    return __half2float(h);
}
__device__ __forceinline__ frag8 mkfrag(unsigned a, unsigned b, unsigned c, unsigned d) {
    u32x4v v = {a, b, c, d};
    return __builtin_bit_cast(frag8, v);
}

// ---------------- 1: zero gcursor (1 block) ---------------------------------
__global__ __launch_bounds__(1024)
void zero_g_kernel(int* __restrict__ gcursor, int n) {
    for (int i = threadIdx.x; i < n; i += 1024) gcursor[i] = 0;
}

// ---------------- 2: split — repack + coarse radix pass ---------------------
__global__ __launch_bounds__(512)
void split_kernel(const float* __restrict__ ev,
                  const int* __restrict__ ei,
                  const float* __restrict__ nf,
                  const float* __restrict__ W,
                  int* __restrict__ gcursor,
                  uint4* __restrict__ gbuf,
                  unsigned* __restrict__ nfT,
                  __hip_bfloat16* __restrict__ w2frag,
                  int n_edges, int n_atoms) {
    __shared__ int hist[256];
    __shared__ int cur[256];
    if (threadIdx.x < 256) hist[threadIdx.x] = 0;
    __syncthreads();

    // ---- folded repack: streams ride this kernel's latency shadow ----------
    const int gtid = blockIdx.x * 512 + threadIdx.x;
    const int gsz  = gridDim.x * 512;
    if (gtid < 2048) {
        const int lane = gtid & 63;
        const int kk   = gtid >> 7;
        const int n    = (((gtid >> 6) & 1) << 4) + (lane & 15);
        const int kb   = kk * 32 + (lane >> 4) * 8;
#pragma unroll
        for (int j = 0; j < 8; ++j)
            w2frag[gtid * 8 + j] = __float2bfloat16(W[(kb + j) * OUTCH + n]);
    }
    // nfT[s][m] = {bf16 nf[s][m] | bf16 nf[s][m+16]}; one uint4 per (s, m-quad)
    const int tq = n_atoms * 4;
    for (int i = gtid; i < tq; i += gsz) {
        const int s = i >> 2, q = (i & 3) * 4;
        const float4 lo = *(const float4*)(nf + s * HIDDEN + q);
        const float4 hi = *(const float4*)(nf + s * HIDDEN + 16 + q);
        uint4 o;
        o.x = (unsigned)bf16bits(lo.x) | ((unsigned)bf16bits(hi.x) << 16);
        o.y = (unsigned)bf16bits(lo.y) | ((unsigned)bf16bits(hi.y) << 16);
        o.z = (unsigned)bf16bits(lo.z) | ((unsigned)bf16bits(hi.z) << 16);
        o.w = (unsigned)bf16bits(lo.w) | ((unsigned)bf16bits(hi.w) << 16);
        *(uint4*)(nfT + s * 16 + q) = o;
    }

    // ---- original split body (r12, unchanged structure) --------------------
    const int e0 = blockIdx.x * CHUNK + threadIdx.x * 4;
    int   sr[4], tg[4];
    float vx[4], vy[4], vz[4];
    const int cnt = min(max(n_edges - e0, 0), 4);
    if (cnt == 4) {
        // e0 % 4 == 0 -> int4 loads and the 3 float4 loads are 16-B aligned
        const int4 s4 = *(const int4*)(ei + e0);
        const int4 t4 = *(const int4*)(ei + n_edges + e0);
        sr[0]=s4.x; sr[1]=s4.y; sr[2]=s4.z; sr[3]=s4.w;
        tg[0]=t4.x; tg[1]=t4.y; tg[2]=t4.z; tg[3]=t4.w;
        const float4 a  = *(const float4*)(ev + 3 * e0 + 0);
        const float4 bq = *(const float4*)(ev + 3 * e0 + 4);
        const float4 cq = *(const float4*)(ev + 3 * e0 + 8);
        vx[0]=a.x;  vy[0]=a.y;  vz[0]=a.z;
        vx[1]=a.w;  vy[1]=bq.x; vz[1]=bq.y;
        vx[2]=bq.z; vy[2]=bq.w; vz[2]=cq.x;
        vx[3]=cq.y; vy[3]=cq.z; vz[3]=cq.w;
    } else {
        for (int j = 0; j < cnt; ++j) {
            const int e = e0 + j;
            sr[j] = ei[e];
            tg[j] = ei[n_edges + e];
            vx[j] = ev[3*e]; vy[j] = ev[3*e+1]; vz[j] = ev[3*e+2];
        }
    }

    for (int j = 0; j < cnt; ++j) atomicAdd(&hist[tg[j] >> 8], 1);
    __syncthreads();
    if (threadIdx.x < 256) {
        const int h = hist[threadIdx.x];
        cur[threadIdx.x] = h ? atomicAdd(&gcursor[threadIdx.x * GSTR], h) : 0;
    }
    __syncthreads();

    for (int j = 0; j < cnt; ++j) {
        const int g = tg[j] >> 8;
        const int pos = atomicAdd(&cur[g], 1);            // LDS; base+i
        if (pos >= GCAP) continue;
        const float rinv = 1.0f /
            fmaxf(sqrtf(vx[j]*vx[j] + vy[j]*vy[j] + vz[j]*vz[j]), 1e-12f);
        uint4 r;
        r.x = (unsigned)(sr[j] & 0xffff) | ((unsigned)f16bits(vx[j]*rinv) << 16);
        r.y = (unsigned)f16bits(vy[j]*rinv) | ((unsigned)f16bits(vz[j]*rinv) << 16);
        r.z = (unsigned)tg[j];
        r.w = 0u;
        gbuf[(size_t)g * GCAP + pos] = r;
    }
}

// ---------------- 3: bucket — fine pass, exclusive range, LDS cursors -------
__global__ __launch_bounds__(1024)
void bucket_kernel(const uint4* __restrict__ gbuf,
                   const int* __restrict__ gcursor,
                   uint2* __restrict__ recs,
                   int* __restrict__ cursor,
                   int n_atoms) {
    __shared__ int lcur[GRP];
    const int g = blockIdx.x;
    if (threadIdx.x < GRP) lcur[threadIdx.x] = 0;
    __syncthreads();
    const int n = min(gcursor[g * GSTR], GCAP);
    const uint4* gb = gbuf + (size_t)g * GCAP;
    for (int i = threadIdx.x; i < n; i += 1024) {
        const uint4 r = gb[i];                            // dense 16-B stream
        const int tgt = (int)r.z;
        const int slot = atomicAdd(&lcur[tgt & (GRP - 1)], 1);  // LDS, ~30 cy
        if (slot < CAP) {
            uint2 d; d.x = r.x; d.y = r.y;
            recs[(size_t)tgt * CAP + slot] = d;           // L2-local slice
        }
    }
    __syncthreads();
    const int a = g * GRP + threadIdx.x;
    if (threadIdx.x < GRP && a < n_atoms)
        cursor[a] = lcur[threadIdx.x];                    // coalesced counts
}

// ---------------- 4: fused MFMA-aggregate + GEMM (unchanged from r12) -------
__global__ __launch_bounds__(1024, 8)
void acc_gemm_kernel(const uint2* __restrict__ recs,
                     const int* __restrict__ cursor,
                     const unsigned* __restrict__ nfT,
                     const __hip_bfloat16* __restrict__ w2frag,
                     const float* __restrict__ bias,
                     float* __restrict__ out,
                     int n_atoms) {
    __shared__ short ldsY[WPB][64 * 18];   // 36864 B: Y rows, 18-short pitch
    __shared__ short ldsAgg[WPB][AGP];     // 18688 B: agg rows, global skew
    __shared__ int   ldsS[WPB][64];        //  4096 B: src*16 (0-padded)
    const int wv   = threadIdx.x >> 6;     // wave id = local atom id
    const int lane = threadIdx.x & 63;
    const int w    = min(blockIdx.x * WPB + wv, n_atoms - 1);

    const int k = min(max(__builtin_amdgcn_readfirstlane(cursor[w]), 0), CAP);

    // ---- phase A: Y rows (one edge per lane; zero rows pad K to 64) --------
    {
        float Yv[16];
#pragma unroll
        for (int q = 0; q < 16; ++q) Yv[q] = 0.f;
        int s = 0;
        if (lane < k) {
            const uint2 rec = recs[(size_t)w * CAP + lane];   // coalesced 8 B
            s = (int)(rec.x & 0xffffu);
            const float x = f16tof((unsigned short)(rec.x >> 16));
            const float y = f16tof((unsigned short)(rec.y & 0xffffu));
            const float z = f16tof((unsigned short)(rec.y >> 16));
            const float x2 = x * x, y2 = y * y, z2 = z * z;
            const float xy = x * y, yz = y * z, xz = x * z;
            const float xmy = x2 - y2;
            const float fz2 = fmaf(5.0f, z2, -1.0f);
            Yv[0]  = C0SH;
            Yv[1]  = 0.4886025119029199f * y;
            Yv[2]  = 0.4886025119029199f * z;
            Yv[3]  = 0.4886025119029199f * x;
            Yv[4]  = 1.0925484305920792f * xy;
            Yv[5]  = 1.0925484305920792f * yz;
            Yv[6]  = 0.31539156525252005f * fmaf(3.0f, z2, -1.0f);
            Yv[7]  = 1.0925484305920792f * xz;
            Yv[8]  = 0.5462742152960396f * xmy;
            Yv[9]  = 0.5900435899266435f * y * fmaf(2.0f, x2, xmy);
            Yv[10] = 2.890611442640554f * xy * z;
            Yv[11] = 0.4570457994644658f * y * fz2;
            Yv[12] = 0.3731763325901154f * z * fmaf(5.0f, z2, -3.0f);
            Yv[13] = 0.4570457994644658f * x * fz2;
            Yv[14] = 1.445305721320277f * z * xmy;
            Yv[15] = 0.5900435899266435f * x * fmaf(-3.0f, y2, x2);
        }
        ldsS[wv][lane] = s << 4;           // premultiplied nfT row offset
        short* yr = &ldsY[wv][lane * 18];
#pragma unroll
        for (int d = 0; d < 8; ++d)
            *(unsigned*)&yr[d * 2] =
                (unsigned)bf16bits(Yv[2 * d]) | ((unsigned)bf16bits(Yv[2 * d + 1]) << 16);
    }
    // order phase-A ds_writes before phase-B ds_reads (same-wave cross-lane)
    asm volatile("s_waitcnt lgkmcnt(0)" ::: "memory");
    __builtin_amdgcn_sched_barrier(0);

    // ---- phase B: MFMA aggregation (nfT paired-h gathers) ------------------
    const int kq = lane >> 4;
    const int m  = lane & 15;     // A: h within tile; B: irrep i; C: col i
    f32x4 acc0 = {0.f, 0.f, 0.f, 0.f};
    f32x4 acc1 = {0.f, 0.f, 0.f, 0.f};
    {
        const short* yrow = &ldsY[wv][0];
        const int* sv = &ldsS[wv][0];
        const int nks = (k > 32) ? 2 : 1;
        for (int ks = 0; ks < nks; ++ks) {
            const int e0 = ks * 32 + kq * 8;
            unsigned g[8];
#pragma unroll
            for (int j = 0; j < 8; ++j)
                g[j] = nfT[sv[e0 + j] + m];   // {nf[s][m] | nf[s][m+16]}
            unsigned bu[4], au0[4], au1[4];
#pragma unroll
            for (int p = 0; p < 4; ++p) {
                const unsigned ylo = *(const unsigned short*)&yrow[(e0 + 2 * p) * 18 + m];
                const unsigned yhi = *(const unsigned short*)&yrow[(e0 + 2 * p + 1) * 18 + m];
                bu[p] = ylo | (yhi << 16);
                const unsigned g0 = g[2 * p], g1 = g[2 * p + 1];
                au0[p] = (g0 & 0xffffu) | (g1 << 16);
                au1[p] = (g0 >> 16) | (g1 & 0xffff0000u);
            }
            const frag8 bf = mkfrag(bu[0], bu[1], bu[2], bu[3]);
            acc0 = __builtin_amdgcn_mfma_f32_16x16x32_bf16(
                mkfrag(au0[0], au0[1], au0[2], au0[3]), bf, acc0, 0, 0, 0);
            acc1 = __builtin_amdgcn_mfma_f32_16x16x32_bf16(
                mkfrag(au1[0], au1[1], au1[2], au1[3]), bf, acc1, 0, 0, 0);
        }
    }

    // ---- phase C: C-frags -> bf16 agg row at pos(k) = k + (k>>6)*8 ---------
    {
        short* arow = &ldsAgg[wv][0];
#pragma unroll
        for (int r = 0; r < 4; ++r) {
            arow[kq * 72 + r * 16 + m]       = (short)bf16bits(acc0[r]);
            arow[kq * 72 + r * 16 + m + 288] = (short)bf16bits(acc1[r]);
        }
    }

    __syncthreads();

    // ---- final GEMM: out[16 atoms][32] = agg @ W + b, waves 0,1 = N-halves -
    if (wv < 2) {
        const int m2   = lane & 15;       // atom within tile
        const int quad = lane >> 4;
        const int nh   = wv;
        const short* wf = (const short*)w2frag;
        f32x4 acc = {0.f, 0.f, 0.f, 0.f};
#pragma unroll
        for (int kk = 0; kk < 16; ++kk) {
            const int sidx = kk * 32 + quad * 8 + (kk >> 1) * 8;
            frag8 a  = *(const frag8*)&ldsAgg[m2][sidx];
            frag8 bb = *(const frag8*)(wf + ((kk * 2 + nh) * 64 + lane) * 8);
            acc = __builtin_amdgcn_mfma_f32_16x16x32_bf16(a, bb, acc, 0, 0, 0);
        }
        const float bi = bias[nh * 16 + m2];
        const int tile0 = blockIdx.x * WPB;
#pragma unroll
        for (int r = 0; r < 4; ++r) {
            const int row = tile0 + quad * 4 + r;   // D: row=quad*4+r, col=m2
            if (row < n_atoms)
                out[(size_t)row * OUTCH + nh * 16 + m2] = acc[r] + bi;
        }
    }
}

// ---------------- launch ---------------------------------------------------
extern "C" void kernel_launch(void* const* d_in, const int* in_sizes, int n_in,
                              void* d_out, int out_size, void* d_ws, size_t ws_size,
                              hipStream_t stream) {
    const float* nf = (const float*)d_in[0];
    const float* ev = (const float*)d_in[1];
    const int*   ei = (const int*)d_in[2];
    const float* W  = (const float*)d_in[3];
    const float* b  = (const float*)d_in[4];
    float* out = (float*)d_out;

    const int n_atoms = in_sizes[0] / HIDDEN;
    const int n_edges = in_sizes[1] / 3;
    const int ngroups = (n_atoms + GRP - 1) / GRP;   // 196

    char* ws = (char*)d_ws;
    size_t off = 0;
    auto carve = [&](size_t bytes) { void* p = ws + off; off = (off + bytes + 255) & ~(size_t)255; return p; };
    uint2*          recs    = (uint2*)carve((size_t)n_atoms * CAP * 8);    // 19.2 MB
    uint4*          gbuf    = (uint4*)carve((size_t)ngroups * GCAP * 16);  // 25.7 MB
    unsigned*       nfT     = (unsigned*)carve((size_t)n_atoms * 16 * 4);  //  3.2 MB
    __hip_bfloat16* w2frag  = (__hip_bfloat16*)carve(2048 * 8 * 2);        //  32 KB
    int*            cursor  = (int*)carve((size_t)n_atoms * 4);            //  0.2 MB
    int*            gcursor = (int*)carve((size_t)ngroups * GSTR * 4);     //  13 KB

    zero_g_kernel<<<1, 1024, 0, stream>>>(gcursor, ngroups * GSTR);

    const int sblocks = (n_edges + CHUNK - 1) / CHUNK;
    split_kernel<<<sblocks, 512, 0, stream>>>(ev, ei, nf, W, gcursor, gbuf,
                                              nfT, w2frag, n_edges, n_atoms);

    bucket_kernel<<<ngroups, 1024, 0, stream>>>(gbuf, gcursor, recs, cursor, n_atoms);

    const int blocks3 = (n_atoms + WPB - 1) / WPB;
    acc_gemm_kernel<<<blocks3, WPB * 64, 0, stream>>>(
        recs, cursor, nfT, w2frag, b, out, n_atoms);
}